// Round 3
// 6540.462 us; speedup vs baseline: 1.9352x; 1.9352x over previous
//
#include <hip/hip_runtime.h>

// ---------------------------------------------------------------------------
// RSSM scan, split-bf16 ("3xBF16") MFMA GEMMs: every operand is a bf16 pair
// (hi, lo) with v ~= hi + lo to 2^-18 rel; D = Ah*Bh + Ah*Bl + Al*Bh in fp32
// accumulators. Structure:
//   cvt2(weights) -> init -> 50x {K1 sa, K2 gi|gh fused, GRU, K3 q1(K=2048,
//   A = det-pair | obs-fp32-split), K4 q-head dual} -> 5x chunks {P2, P3}
//
// Pair-path staging uses global_load_lds (16B DMA) into a linear 64x64 LDS
// tile with XOR-16B swizzle (phys = row*128 + (cb ^ ((row&7)<<4))). Swizzle
// is applied on the global SOURCE address (per-lane) and on the ds_read side
// — gload_lds dest stays linear (rule #21). fp32-A staging (P2 / K3-obs)
// reg-stages with rotated col chunks (2-way). All DMA sources verified
// in-bounds and 16B-aligned at every call site.
// ---------------------------------------------------------------------------

typedef __attribute__((ext_vector_type(8))) short bf16x8;
typedef __attribute__((ext_vector_type(4))) float f32x4;

typedef const __attribute__((address_space(1))) void* gas_ptr;
typedef __attribute__((address_space(3))) void* las_ptr;

__device__ inline void gl_lds16(const void* g, void* l) {
  __builtin_amdgcn_global_load_lds((gas_ptr)g, (las_ptr)l, 16, 0, 0);
}

__device__ inline ushort f2b(float f) {                      // fp32 -> bf16 RNE
  unsigned int x = __float_as_uint(f);
  unsigned int r = (x + 0x7fffu + ((x >> 16) & 1u)) >> 16;
  return (ushort)r;
}
__device__ inline float b2f(ushort u) { return __uint_as_float(((unsigned int)u) << 16); }
__device__ inline float eluf(float x) { return x > 0.f ? x : expm1f(x); }

// split 16 contiguous fp32 into bf16 hi/lo
__device__ inline void split16(const float* __restrict__ p, ushort* h, ushort* l) {
#pragma unroll
  for (int i = 0; i < 16; i += 4) {
    float4 v = *(const float4*)(p + i);
    float vv[4] = {v.x, v.y, v.z, v.w};
#pragma unroll
    for (int j = 0; j < 4; ++j) {
      ushort hh = f2b(vv[j]);
      h[i + j] = hh;
      l[i + j] = f2b(vv[j] - b2f(hh));
    }
  }
}

// ---------------------------------------------------------------------------
// Stage one 64x64 ushort tile (rows row0.., cols col0.. of row-major src, ld)
// into an 8KB linear LDS tile via global_load_lds, with the XOR-16B swizzle
// folded into the per-lane global source address. Wave w covers rows
// [16w,16w+16) in two 1KB calls (8 rows each).
// ---------------------------------------------------------------------------
__device__ inline void stage_pair(const ushort* __restrict__ src, long row0, long ld,
                                  long col0, ushort* lds, int w, int lane) {
  int rsub = lane >> 3;                                    // 0..7
  long r = row0 + (w << 4) + rsub;
  long c = col0 + (long)(((lane & 7) ^ rsub) << 3);        // swizzled source col
  const ushort* g = src + r * ld + c;
  ushort* d = lds + (w << 10);                             // wave-uniform base
  gl_lds16(g, d);                                          // rows 16w+0..7
  gl_lds16(g + (ld << 3), d + 512);                        // rows 16w+8..15
}

// fp32 A row staging: thread handles 16 floats of row srow, chunk sci
// (col rotation keeps ds_write 2-way). src already includes row*ld + colbase.
__device__ inline void stage_f32(const float* __restrict__ src,
                                 ushort* Ash, ushort* Asl, int srow, int sci) {
  ushort h[16], l[16];
  split16(src + (sci << 4), h, l);
  int sw = (srow & 7) << 4;
  char* bh = (char*)Ash + srow * 128;
  char* bl = (char*)Asl + srow * 128;
  int c0 = sci << 5;
  *(int4*)(bh + (c0 ^ sw))        = ((int4*)h)[0];
  *(int4*)(bh + ((c0 + 16) ^ sw)) = ((int4*)h)[1];
  *(int4*)(bl + (c0 ^ sw))        = ((int4*)l)[0];
  *(int4*)(bl + ((c0 + 16) ^ sw)) = ((int4*)l)[1];
}

// swizzled fragment read: 16B-aligned chunk at logical (row, kbyte)
__device__ inline bf16x8 frag(const ushort* lds, int row, int kb) {
  return *(const bf16x8*)((const char*)lds + (row << 7) + (kb ^ ((row & 7) << 4)));
}

__global__ __launch_bounds__(256) void k_cvt2(const float* __restrict__ src,
                                              ushort* __restrict__ hi,
                                              ushort* __restrict__ lo, int n) {
  int i = blockIdx.x * 256 + threadIdx.x;
  if (i < n) {
    float v = src[i];
    ushort h = f2b(v);
    hi[i] = h;
    lo[i] = f2b(v - b2f(h));
  }
}

#define MFMA __builtin_amdgcn_mfma_f32_16x16x32_bf16

// ---------------------------------------------------------------------------
// Split-pair GEMM: out[m][n] = act( A[m][:] . B[n][:] + bias[n] )
// A sources: pair arrays (Ah,Al) or fp32 (Af, split in staging).
// Col-dual (n_split): n0>=n_split -> A2/B2/bias2 (fused gi|gh).
// K-dual (k_split):  k>=k_split  -> A from A2f (fp32) (x_post = [det|obs]).
// Output: fp32 (out_f) and/or bf16 pair (out_hi/out_lo).
// ---------------------------------------------------------------------------
__global__ __launch_bounds__(256) void k_gemm(
    const float* __restrict__ A1f, const ushort* __restrict__ A1h,
    const ushort* __restrict__ A1l, int lda1,
    const float* __restrict__ A2f, const ushort* __restrict__ A2h,
    const ushort* __restrict__ A2l, int lda2,
    const ushort* __restrict__ B1h, const ushort* __restrict__ B1l, int ldb1,
    const ushort* __restrict__ B2h, const ushort* __restrict__ B2l, int ldb2,
    int n_split, int k_split,
    const float* __restrict__ bias1, const float* __restrict__ bias2,
    ushort* __restrict__ out_hi, ushort* __restrict__ out_lo,
    float* __restrict__ out_f, int ld_out, int K, int do_elu)
{
  __shared__ __align__(16) ushort Ash[64 * 64], Asl[64 * 64];
  __shared__ __align__(16) ushort Bsh[64 * 64], Bsl[64 * 64];

  int n0 = blockIdx.x * 64, m0 = blockIdx.y * 64;
  const float* af1 = A1f; const ushort* ah1 = A1h; const ushort* al1 = A1l;
  int la1 = lda1;
  const ushort* bhp = B1h; const ushort* blp = B1l; int lb = ldb1;
  const float* bp = bias1;
  int brow0 = n0;
  if (n0 >= n_split) {
    af1 = A2f; ah1 = A2h; al1 = A2l; la1 = lda2;
    bhp = B2h; blp = B2l; lb = ldb2; bp = bias2; brow0 = n0 - n_split;
  }

  int tid = threadIdx.x;
  int lane = tid & 63, w = tid >> 6;
  int wr = (w >> 1) << 5, wc = (w & 1) << 5;
  int lr = lane & 15, lq = lane >> 4;
  int srow = tid >> 2, sci = (tid + (tid >> 2)) & 3;

  f32x4 acc[2][2] = {};

  for (int k0 = 0; k0 < K; k0 += 64) {
    __syncthreads();                           // prev-iter LDS reads done
    stage_pair(bhp, brow0, lb, k0, Bsh, w, lane);
    stage_pair(blp, brow0, lb, k0, Bsl, w, lane);
    if (k0 >= k_split) {                       // K3 second half: fp32 obs
      stage_f32(A2f + (long)(m0 + srow) * lda2 + (k0 - k_split), Ash, Asl, srow, sci);
    } else if (af1) {                          // fp32 A, split in staging
      stage_f32(af1 + (long)(m0 + srow) * la1 + k0, Ash, Asl, srow, sci);
    } else {                                   // pre-split pair A via DMA
      stage_pair(ah1, m0, la1, k0, Ash, w, lane);
      stage_pair(al1, m0, la1, k0, Asl, w, lane);
    }
    __syncthreads();                           // drains vmcnt+lgkm: LDS ready
#pragma unroll
    for (int kk = 0; kk < 2; ++kk) {
      int kb = kk * 64 + lq * 16;
      bf16x8 a0h = frag(Ash, wr + lr, kb);
      bf16x8 a1h = frag(Ash, wr + 16 + lr, kb);
      bf16x8 a0l = frag(Asl, wr + lr, kb);
      bf16x8 a1l = frag(Asl, wr + 16 + lr, kb);
      bf16x8 b0h = frag(Bsh, wc + lr, kb);
      bf16x8 b1h = frag(Bsh, wc + 16 + lr, kb);
      bf16x8 b0l = frag(Bsl, wc + lr, kb);
      bf16x8 b1l = frag(Bsl, wc + 16 + lr, kb);
      acc[0][0] = MFMA(a0h, b0h, acc[0][0], 0, 0, 0);
      acc[0][0] = MFMA(a0h, b0l, acc[0][0], 0, 0, 0);
      acc[0][0] = MFMA(a0l, b0h, acc[0][0], 0, 0, 0);
      acc[0][1] = MFMA(a0h, b1h, acc[0][1], 0, 0, 0);
      acc[0][1] = MFMA(a0h, b1l, acc[0][1], 0, 0, 0);
      acc[0][1] = MFMA(a0l, b1h, acc[0][1], 0, 0, 0);
      acc[1][0] = MFMA(a1h, b0h, acc[1][0], 0, 0, 0);
      acc[1][0] = MFMA(a1h, b0l, acc[1][0], 0, 0, 0);
      acc[1][0] = MFMA(a1l, b0h, acc[1][0], 0, 0, 0);
      acc[1][1] = MFMA(a1h, b1h, acc[1][1], 0, 0, 0);
      acc[1][1] = MFMA(a1h, b1l, acc[1][1], 0, 0, 0);
      acc[1][1] = MFMA(a1l, b1h, acc[1][1], 0, 0, 0);
    }
  }

#pragma unroll
  for (int i = 0; i < 2; ++i)
#pragma unroll
    for (int j = 0; j < 2; ++j) {
      int colL = wc + j * 16 + lr;
      int col = n0 + colL;
      float bv = bp ? bp[brow0 + colL] : 0.f;
#pragma unroll
      for (int r = 0; r < 4; ++r) {
        int row = m0 + wr + i * 16 + lq * 4 + r;  // C/D: col=lane&15,row=quad*4+reg
        float v = acc[i][j][r] + bv;
        if (do_elu) v = eluf(v);
        long idx = (long)row * ld_out + col;
        if (out_f) out_f[idx] = v;
        if (out_hi) {
          ushort hh = f2b(v);
          out_hi[idx] = hh;
          out_lo[idx] = f2b(v - b2f(hh));
        }
      }
    }
}

// ---------------------------------------------------------------------------
// Distribution head (split-pair): raw2 = A @ W.T + bias, W [512][1024] pair.
// Block computes mean tile (rows n0..) + std tile (rows 256+n0..); epilogue:
// std = softplus(raw)+0.1, stoch = mean + std*noise; writes fp32 out triple
// at [rg][coloff + {0,256,512}]; optional stoch pair carry (ld 320).
// ---------------------------------------------------------------------------
__global__ __launch_bounds__(256) void k_head(
    const ushort* __restrict__ Ah, const ushort* __restrict__ Al,  // [M][1024]
    const ushort* __restrict__ Wh, const ushort* __restrict__ Wl,  // [512][1024]
    const float* __restrict__ bias, const float* __restrict__ noise,
    float* __restrict__ out, long out_row0, int coloff,
    ushort* __restrict__ st_hi, ushort* __restrict__ st_lo)
{
  __shared__ __align__(16) ushort Ash[64*64], Asl[64*64];
  __shared__ __align__(16) ushort B0h[64*64], B0l[64*64];
  __shared__ __align__(16) ushort B1h[64*64], B1l[64*64];

  const int K = 1024;
  int n0 = blockIdx.x * 64, m0 = blockIdx.y * 64;
  int tid = threadIdx.x;
  int lane = tid & 63, w = tid >> 6;
  int wr = (w >> 1) << 5, wc = (w & 1) << 5;
  int lr = lane & 15, lq = lane >> 4;

  f32x4 acc[2][2][2] = {};   // [set 0=mean 1=std][i][j]

  for (int k0 = 0; k0 < K; k0 += 64) {
    __syncthreads();
    stage_pair(Ah, m0,       K, k0, Ash, w, lane);
    stage_pair(Al, m0,       K, k0, Asl, w, lane);
    stage_pair(Wh, n0,       K, k0, B0h, w, lane);
    stage_pair(Wl, n0,       K, k0, B0l, w, lane);
    stage_pair(Wh, 256 + n0, K, k0, B1h, w, lane);
    stage_pair(Wl, 256 + n0, K, k0, B1l, w, lane);
    __syncthreads();
#pragma unroll
    for (int kk = 0; kk < 2; ++kk) {
      int kb = kk * 64 + lq * 16;
      bf16x8 a0h = frag(Ash, wr + lr, kb);
      bf16x8 a1h = frag(Ash, wr + 16 + lr, kb);
      bf16x8 a0l = frag(Asl, wr + lr, kb);
      bf16x8 a1l = frag(Asl, wr + 16 + lr, kb);
      bf16x8 p0h = frag(B0h, wc + lr, kb);
      bf16x8 p1h = frag(B0h, wc + 16 + lr, kb);
      bf16x8 p0l = frag(B0l, wc + lr, kb);
      bf16x8 p1l = frag(B0l, wc + 16 + lr, kb);
      bf16x8 q0h = frag(B1h, wc + lr, kb);
      bf16x8 q1h = frag(B1h, wc + 16 + lr, kb);
      bf16x8 q0l = frag(B1l, wc + lr, kb);
      bf16x8 q1l = frag(B1l, wc + 16 + lr, kb);
      acc[0][0][0] = MFMA(a0h, p0h, acc[0][0][0], 0, 0, 0);
      acc[0][0][0] = MFMA(a0h, p0l, acc[0][0][0], 0, 0, 0);
      acc[0][0][0] = MFMA(a0l, p0h, acc[0][0][0], 0, 0, 0);
      acc[0][0][1] = MFMA(a0h, p1h, acc[0][0][1], 0, 0, 0);
      acc[0][0][1] = MFMA(a0h, p1l, acc[0][0][1], 0, 0, 0);
      acc[0][0][1] = MFMA(a0l, p1h, acc[0][0][1], 0, 0, 0);
      acc[0][1][0] = MFMA(a1h, p0h, acc[0][1][0], 0, 0, 0);
      acc[0][1][0] = MFMA(a1h, p0l, acc[0][1][0], 0, 0, 0);
      acc[0][1][0] = MFMA(a1l, p0h, acc[0][1][0], 0, 0, 0);
      acc[0][1][1] = MFMA(a1h, p1h, acc[0][1][1], 0, 0, 0);
      acc[0][1][1] = MFMA(a1h, p1l, acc[0][1][1], 0, 0, 0);
      acc[0][1][1] = MFMA(a1l, p1h, acc[0][1][1], 0, 0, 0);
      acc[1][0][0] = MFMA(a0h, q0h, acc[1][0][0], 0, 0, 0);
      acc[1][0][0] = MFMA(a0h, q0l, acc[1][0][0], 0, 0, 0);
      acc[1][0][0] = MFMA(a0l, q0h, acc[1][0][0], 0, 0, 0);
      acc[1][0][1] = MFMA(a0h, q1h, acc[1][0][1], 0, 0, 0);
      acc[1][0][1] = MFMA(a0h, q1l, acc[1][0][1], 0, 0, 0);
      acc[1][0][1] = MFMA(a0l, q1h, acc[1][0][1], 0, 0, 0);
      acc[1][1][0] = MFMA(a1h, q0h, acc[1][1][0], 0, 0, 0);
      acc[1][1][0] = MFMA(a1h, q0l, acc[1][1][0], 0, 0, 0);
      acc[1][1][0] = MFMA(a1l, q0h, acc[1][1][0], 0, 0, 0);
      acc[1][1][1] = MFMA(a1h, q1h, acc[1][1][1], 0, 0, 0);
      acc[1][1][1] = MFMA(a1h, q1l, acc[1][1][1], 0, 0, 0);
      acc[1][1][1] = MFMA(a1l, q1h, acc[1][1][1], 0, 0, 0);
    }
  }

#pragma unroll
  for (int i = 0; i < 2; ++i)
#pragma unroll
    for (int j = 0; j < 2; ++j) {
      int c = n0 + wc + j * 16 + lr;
      float bm = bias[c];
      float bs = bias[256 + c];
#pragma unroll
      for (int r = 0; r < 4; ++r) {
        int m = m0 + wr + i * 16 + lq * 4 + r;
        long rg = out_row0 + m;
        float mean = acc[0][i][j][r] + bm;
        float sraw = acc[1][i][j][r] + bs;
        float stdv = (sraw > 15.f ? sraw : log1pf(expf(sraw))) + 0.1f;
        float nz = noise[rg * 256 + c];
        float st = mean + stdv * nz;
        long ob = rg * 2560 + coloff + c;
        out[ob]       = mean;
        out[ob + 256] = stdv;
        out[ob + 512] = st;
        if (st_hi) {
          ushort hh = f2b(st);
          st_hi[m * 320 + c] = hh;
          st_lo[m * 320 + c] = f2b(st - b2f(hh));
        }
      }
    }
}

// ---------------------------------------------------------------------------
__global__ __launch_bounds__(256) void k_gru(
    const float* __restrict__ gates, float* __restrict__ det_f,
    ushort* __restrict__ det_h, ushort* __restrict__ det_l,
    float* __restrict__ out, const float* __restrict__ act,
    ushort* __restrict__ sa_h, ushort* __restrict__ sa_l, int t)
{
  int idx = blockIdx.x * 256 + threadIdx.x;   // 512*1024
  int row = idx >> 10, col = idx & 1023;
  long g = (long)row * 6144;
  float i_r = gates[g + col];
  float i_z = gates[g + 1024 + col];
  float i_n = gates[g + 2048 + col];
  float h_r = gates[g + 3072 + col];
  float h_z = gates[g + 4096 + col];
  float h_n = gates[g + 5120 + col];
  float rr = 1.f / (1.f + expf(-(i_r + h_r)));
  float zz = 1.f / (1.f + expf(-(i_z + h_z)));
  float nn = tanhf(i_n + rr * h_n);
  float h  = det_f[idx];
  float hn = (1.f - zz) * nn + zz * h;
  det_f[idx] = hn;
  ushort hh = f2b(hn);
  det_h[idx] = hh;
  det_l[idx] = f2b(hn - b2f(hh));
  out[((long)t * 512 + row) * 2560 + 1536 + col] = hn;
  if (col < 64 && t + 1 < 50) {
    float a = act[(((long)(t + 1)) * 512 + row) * 64 + col];
    ushort ahh = f2b(a);
    sa_h[row * 320 + 256 + col] = ahh;
    sa_l[row * 320 + 256 + col] = f2b(a - b2f(ahh));
  }
}

__global__ __launch_bounds__(256) void k_init(
    const float* __restrict__ is0, const float* __restrict__ id0,
    const float* __restrict__ act,
    ushort* __restrict__ sa_h, ushort* __restrict__ sa_l,
    ushort* __restrict__ det_h, ushort* __restrict__ det_l,
    float* __restrict__ det_f)
{
  int idx = blockIdx.x * 256 + threadIdx.x;   // 512*1024
  int row = idx >> 10, col = idx & 1023;
  float dv = id0[idx];
  ushort hh = f2b(dv);
  det_h[idx] = hh;
  det_l[idx] = f2b(dv - b2f(hh));
  det_f[idx] = dv;
  if (col < 256) {
    float v = is0[row * 256 + col];
    ushort vh = f2b(v);
    sa_h[row * 320 + col] = vh;
    sa_l[row * 320 + col] = f2b(v - b2f(vh));
  } else if (col < 320) {
    float v = act[row * 64 + (col - 256)];
    ushort vh = f2b(v);
    sa_h[row * 320 + col] = vh;
    sa_l[row * 320 + col] = f2b(v - b2f(vh));
  }
}

// ---------------------------------------------------------------------------
extern "C" void kernel_launch(void* const* d_in, const int* in_sizes, int n_in,
                              void* d_out, int out_size, void* d_ws, size_t ws_size,
                              hipStream_t stream) {
  const float* obs   = (const float*)d_in[0];
  const float* act   = (const float*)d_in[1];
  const float* is0   = (const float*)d_in[2];
  const float* id0   = (const float*)d_in[3];
  const float* npri  = (const float*)d_in[4];
  const float* npost = (const float*)d_in[5];
  const float* Wsa = (const float*)d_in[6];  const float* bsa = (const float*)d_in[7];
  const float* Wih = (const float*)d_in[8];  const float* bih = (const float*)d_in[9];
  const float* Whh = (const float*)d_in[10]; const float* bhh = (const float*)d_in[11];
  const float* Wp1 = (const float*)d_in[12]; const float* bp1 = (const float*)d_in[13];
  const float* Wp2 = (const float*)d_in[14]; const float* bp2 = (const float*)d_in[15];
  const float* Wq1 = (const float*)d_in[16]; const float* bq1 = (const float*)d_in[17];
  const float* Wq2 = (const float*)d_in[18]; const float* bq2 = (const float*)d_in[19];
  float* out = (float*)d_out;

  char* ws = (char*)d_ws;   // ~85.9 MB total
  size_t o = 0;
  auto alloc = [&](size_t bytes) { char* p = ws + o; o += (bytes + 255) & ~255ULL; return p; };
  ushort* Wsa_h = (ushort*)alloc(655360);    ushort* Wsa_l = (ushort*)alloc(655360);
  ushort* Wih_h = (ushort*)alloc(6291456);   ushort* Wih_l = (ushort*)alloc(6291456);
  ushort* Whh_h = (ushort*)alloc(6291456);   ushort* Whh_l = (ushort*)alloc(6291456);
  ushort* Wp1_h = (ushort*)alloc(2097152);   ushort* Wp1_l = (ushort*)alloc(2097152);
  ushort* Wp2_h = (ushort*)alloc(1048576);   ushort* Wp2_l = (ushort*)alloc(1048576);
  ushort* Wq1_h = (ushort*)alloc(4194304);   ushort* Wq1_l = (ushort*)alloc(4194304);
  ushort* Wq2_h = (ushort*)alloc(1048576);   ushort* Wq2_l = (ushort*)alloc(1048576);
  float*  gates = (float*)alloc(12582912);
  ushort* sain_h = (ushort*)alloc(327680);   ushort* sain_l = (ushort*)alloc(327680);
  ushort* sa_h  = (ushort*)alloc(1048576);   ushort* sa_l  = (ushort*)alloc(1048576);
  ushort* det_h = (ushort*)alloc(1048576);   ushort* det_l = (ushort*)alloc(1048576);
  float*  det_f = (float*)alloc(2097152);
  ushort* qh1_h = (ushort*)alloc(1048576);   ushort* qh1_l = (ushort*)alloc(1048576);
  ushort* ph1_h = (ushort*)alloc(10485760);  ushort* ph1_l = (ushort*)alloc(10485760);

  const int NS = 1 << 30;
  const ushort* NH = nullptr;

  // weight splits
  k_cvt2<<<(327680+255)/256, 256, 0, stream>>>(Wsa, Wsa_h, Wsa_l, 327680);
  k_cvt2<<<(3145728+255)/256, 256, 0, stream>>>(Wih, Wih_h, Wih_l, 3145728);
  k_cvt2<<<(3145728+255)/256, 256, 0, stream>>>(Whh, Whh_h, Whh_l, 3145728);
  k_cvt2<<<(1048576+255)/256, 256, 0, stream>>>(Wp1, Wp1_h, Wp1_l, 1048576);
  k_cvt2<<<(524288+255)/256, 256, 0, stream>>>(Wp2, Wp2_h, Wp2_l, 524288);
  k_cvt2<<<(2097152+255)/256, 256, 0, stream>>>(Wq1, Wq1_h, Wq1_l, 2097152);
  k_cvt2<<<(524288+255)/256, 256, 0, stream>>>(Wq2, Wq2_h, Wq2_l, 524288);

  k_init<<<2048, 256, 0, stream>>>(is0, id0, act, sain_h, sain_l, det_h, det_l, det_f);

  for (int t = 0; t < 50; ++t) {
    // K1: sa = elu([stoch,act] @ Wsa.T + bsa), K=320
    k_gemm<<<dim3(16, 8), 256, 0, stream>>>(
        nullptr, sain_h, sain_l, 320, nullptr, NH, NH, 0,
        Wsa_h, Wsa_l, 320, NH, NH, 0, NS, NS, bsa, nullptr,
        sa_h, sa_l, nullptr, 1024, 320, 1);
    // K2: gates = [sa@Wih.T + bih | det@Whh.T + bhh], col-split at 3072
    k_gemm<<<dim3(96, 8), 256, 0, stream>>>(
        nullptr, sa_h, sa_l, 1024, nullptr, det_h, det_l, 1024,
        Wih_h, Wih_l, 1024, Whh_h, Whh_l, 1024, 3072, NS, bih, bhh,
        nullptr, nullptr, gates, 6144, 1024, 0);
    k_gru<<<2048, 256, 0, stream>>>(gates, det_f, det_h, det_l, out, act,
                                    sain_h, sain_l, t);
    // K3: qh1 = elu(x_post @ Wq1.T + bq1), K=2048, A k-split at 1024:
    //     k<1024 det pair, k>=1024 obs_t fp32 (split in staging)
    k_gemm<<<dim3(16, 8), 256, 0, stream>>>(
        nullptr, det_h, det_l, 1024,
        obs + (long)t * 524288, NH, NH, 1024,
        Wq1_h, Wq1_l, 2048, NH, NH, 0, NS, 1024, bq1, nullptr,
        qh1_h, qh1_l, nullptr, 1024, 2048, 1);
    // K4: q-head -> out[t] cols 768.., stoch pair carry -> sa_in
    k_head<<<dim3(4, 8), 256, 0, stream>>>(qh1_h, qh1_l, Wq2_h, Wq2_l, bq2,
        npost, out, (long)t * 512, 768, sain_h, sain_l);
  }

  // Prior branch in 5 chunks of 10 timesteps (5120 rows each)
  for (int c = 0; c < 5; ++c) {
    long r0 = (long)c * 5120;
    // P2: ph1 = elu(deter @ Wp1.T + bp1), deter read fp32 from out
    k_gemm<<<dim3(16, 80), 256, 0, stream>>>(
        out + 1536 + r0 * 2560, NH, NH, 2560, nullptr, NH, NH, 0,
        Wp1_h, Wp1_l, 1024, NH, NH, 0, NS, NS, bp1, nullptr,
        ph1_h, ph1_l, nullptr, 1024, 1024, 1);
    // P3: p-head -> out cols 0..767
    k_head<<<dim3(4, 80), 256, 0, stream>>>(ph1_h, ph1_l, Wp2_h, Wp2_l, bp2,
        npri, out, r0, 0, nullptr, nullptr);
  }
}